// Round 1
// baseline (3214.177 us; speedup 1.0000x reference)
//
#include <hip/hip_runtime.h>
#include <hip/hip_bf16.h>

#define N_NODES 100000
#define N_EDGES 3200000
#define N_GRAPHS 4096
#define N_REL 5
#define N_BASES 4
#define HID 32
#define SEG (N_NODES*N_REL)

// ---------------- CSR construction ----------------

static __global__ __launch_bounds__(256) void k_hist(const int* __restrict__ ei,
                                                     const int* __restrict__ et,
                                                     int* __restrict__ cnt) {
    int e = blockIdx.x * 256 + threadIdx.x;
    if (e < N_EDGES) {
        int dst = ei[N_EDGES + e];
        int r = et[e];
        atomicAdd(&cnt[dst * N_REL + r], 1);
    }
}

// Block-level scan + atomic base allocation. Segment placement order is
// nondeterministic across blocks but any non-overlapping allocation is valid.
static __global__ __launch_bounds__(256) void k_alloc(const int* __restrict__ cnt,
                                                      int* __restrict__ offs,
                                                      int* __restrict__ cur,
                                                      int* __restrict__ gcnt) {
    __shared__ int sdata[256];
    __shared__ int sbase;
    int t = threadIdx.x;
    int base = blockIdx.x * 2048 + t * 8;
    int v[8]; int s = 0;
#pragma unroll
    for (int j = 0; j < 8; j++) {
        int idx = base + j;
        int c = (idx < SEG) ? cnt[idx] : 0;
        v[j] = s; s += c;
    }
    sdata[t] = s;
    __syncthreads();
    for (int off = 1; off < 256; off <<= 1) {
        int x = (t >= off) ? sdata[t - off] : 0;
        __syncthreads();
        sdata[t] += x;
        __syncthreads();
    }
    int incl = sdata[t];
    int excl = incl - s;
    if (t == 255) sbase = atomicAdd(gcnt, incl);   // incl at t=255 == block total
    __syncthreads();
    int b0 = sbase + excl;
#pragma unroll
    for (int j = 0; j < 8; j++) {
        int idx = base + j;
        if (idx < SEG) { int o = b0 + v[j]; offs[idx] = o; cur[idx] = o; }
    }
}

static __global__ __launch_bounds__(256) void k_scatter(const int* __restrict__ ei,
                                                        const int* __restrict__ et,
                                                        int* __restrict__ cur,
                                                        int* __restrict__ srcs) {
    int e = blockIdx.x * 256 + threadIdx.x;
    if (e < N_EDGES) {
        int src = ei[e];
        int dst = ei[N_EDGES + e];
        int r = et[e];
        int p = atomicAdd(&cur[dst * N_REL + r], 1);
        srcs[p] = src;
    }
}

// ---------------- layer-0 input padding (4 -> 32 dims, zero fill) ----------------

static __global__ __launch_bounds__(256) void k_pad(const float* __restrict__ x,
                                                    float* __restrict__ x32) {
    int tid = blockIdx.x * 256 + threadIdx.x;   // < N_NODES*32
    int n = tid >> 5, i = tid & 31;
    x32[tid] = (i < 4) ? x[(n << 2) + i] : 0.f;
}

// ---------------- per-layer weight prep ----------------
// Wc[k][o], k in [0,160): k<128 -> basis_b rows (b=k>>5, i=k&31, zero-padded),
// k>=128 -> root rows. Stored packed for float4 phase-2 reads:
// Wp[kc*128 + o*4 + j] = Wc[kc*4+j][o],  kc in [0,40).
static __global__ __launch_bounds__(256) void k_wprep(const float* __restrict__ basis,
                                                      const float* __restrict__ root,
                                                      int in_c, float* __restrict__ Wp) {
    int idx = blockIdx.x * 256 + threadIdx.x;   // < 5120
    int kc = idx >> 7, rem = idx & 127;
    int o = rem >> 2, j = rem & 3;
    int k = kc * 4 + j;
    float v;
    if (k < 128) {
        int b = k >> 5, ii = k & 31;
        v = (ii < in_c) ? basis[(b * in_c + ii) * HID + o] : 0.f;
    } else {
        int ii = k - 128;
        v = (ii < in_c) ? root[ii * HID + o] : 0.f;
    }
    Wp[kc * 128 + o * 4 + j] = v;
}

// ---------------- fused RGCN layer ----------------
// Block = 256 thr = 4 waves; wave owns 4 nodes. Phase 1: per-(node,rel)
// segment sums (lane = dim, half-waves split edges, unroll-4 for MLP).
// Basis-folded: aggB[b][i] = sum_r comp[r][b] * mean_r[i]. Phase 2: K=160
// float4 LDS matvec, W staged once per block, + bias, tanh, dual store.
static __global__ __launch_bounds__(256) void k_layer(
    const float* __restrict__ hin, const int* __restrict__ offs,
    const int* __restrict__ cnt, const int* __restrict__ srcs,
    const float* __restrict__ comp, const float* __restrict__ Wp,
    const float* __restrict__ bias, float* __restrict__ hout,
    float* __restrict__ hall, int hall_off) {
    __shared__ __align__(16) float sW[5120];          // 20 KB
    __shared__ __align__(16) float sAgg[4][4][160];   // 10.25 KB
    __shared__ float sComp[20];
    int t = threadIdx.x;
#pragma unroll
    for (int idx = t; idx < 5120; idx += 256) sW[idx] = Wp[idx];
    if (t < 20) sComp[t] = comp[t];
    __syncthreads();

    int wave = t >> 6, lane = t & 63, i = lane & 31, half = lane >> 5;
    int nbase = blockIdx.x * 16 + wave * 4;   // N_NODES = 6250*16 exactly

    for (int nn = 0; nn < 4; nn++) {
        int n = nbase + nn;
        float a0 = 0.f, a1 = 0.f, a2 = 0.f, a3 = 0.f;
        for (int r = 0; r < N_REL; r++) {
            int s5 = n * N_REL + r;
            int base = offs[s5];
            int c = cnt[s5];
            if (c > 0) {
                float S = 0.f;
                int last = base + c - 1;
                // half-wave processes edges {half, half+2, ...}; 4 at a time,
                // indices clamped so all loads are valid, masked adds.
                for (int k = half; k < c; k += 8) {
                    int p0 = base + k, p1 = p0 + 2, p2 = p0 + 4, p3 = p0 + 6;
                    int q0 = min(p0, last), q1 = min(p1, last);
                    int q2 = min(p2, last), q3 = min(p3, last);
                    int s0 = srcs[q0], s1 = srcs[q1], s2 = srcs[q2], s3 = srcs[q3];
                    float h0 = hin[(s0 << 5) + i], h1 = hin[(s1 << 5) + i];
                    float h2 = hin[(s2 << 5) + i], h3 = hin[(s3 << 5) + i];
                    if (p0 <= last) S += h0;
                    if (p1 <= last) S += h1;
                    if (p2 <= last) S += h2;
                    if (p3 <= last) S += h3;
                }
                S += __shfl_xor(S, 32);
                float Sv = S * (1.f / (float)c);
                a0 += sComp[r * 4 + 0] * Sv;
                a1 += sComp[r * 4 + 1] * Sv;
                a2 += sComp[r * 4 + 2] * Sv;
                a3 += sComp[r * 4 + 3] * Sv;
            }
        }
        if (half == 0) {
            sAgg[wave][nn][i]       = a0;
            sAgg[wave][nn][32 + i]  = a1;
            sAgg[wave][nn][64 + i]  = a2;
            sAgg[wave][nn][96 + i]  = a3;
            sAgg[wave][nn][128 + i] = hin[(n << 5) + i];   // self
        }
    }
    __syncthreads();

    // phase 2: half0 -> nodes 0,1 ; half1 -> nodes 2,3
    int mynode = half * 2;
    const float4* wv = (const float4*)sW;
    const float4* aA = (const float4*)&sAgg[wave][mynode][0];
    const float4* aB = (const float4*)&sAgg[wave][mynode + 1][0];
    float acc0 = 0.f, acc1 = 0.f;
#pragma unroll
    for (int kc = 0; kc < 40; kc++) {
        float4 w4 = wv[kc * 32 + i];
        float4 a4 = aA[kc];
        float4 b4 = aB[kc];
        acc0 += a4.x * w4.x + a4.y * w4.y + a4.z * w4.z + a4.w * w4.w;
        acc1 += b4.x * w4.x + b4.y * w4.y + b4.z * w4.z + b4.w * w4.w;
    }
    float bi = bias[i];
    float v0 = tanhf(acc0 + bi);
    float v1 = tanhf(acc1 + bi);
    int n0 = nbase + mynode;
    hout[(n0 << 5) + i] = v0;
    hout[((n0 + 1) << 5) + i] = v1;
    hall[n0 * 128 + hall_off + i] = v0;
    hall[(n0 + 1) * 128 + hall_off + i] = v1;
}

// ---------------- final MLP ----------------
// wave per graph: g = [h[user], h[item]] (256) in LDS, lane computes z[lane]
// and z[lane+64], then out = relu(z) . w2 via shuffle reduction.
static __global__ __launch_bounds__(256) void k_mlp(
    const float* __restrict__ hall, const int* __restrict__ uidx,
    const int* __restrict__ iidx, const float* __restrict__ w1,
    const float* __restrict__ b1, const float* __restrict__ w2,
    const float* __restrict__ b2, float* __restrict__ out) {
    __shared__ float sg[4][256];
    int t = threadIdx.x, wave = t >> 6, lane = t & 63;
    int g = blockIdx.x * 4 + wave;
    int u = uidx[g], it = iidx[g];
    sg[wave][lane]       = hall[u * 128 + lane];
    sg[wave][64 + lane]  = hall[u * 128 + 64 + lane];
    sg[wave][128 + lane] = hall[it * 128 + lane];
    sg[wave][192 + lane] = hall[it * 128 + 64 + lane];
    __syncthreads();
    float a0 = b1[lane], a1 = b1[64 + lane];
#pragma unroll 4
    for (int k = 0; k < 256; k++) {
        float gk = sg[wave][k];
        a0 += gk * w1[k * 128 + lane];
        a1 += gk * w1[k * 128 + 64 + lane];
    }
    float z0 = fmaxf(a0, 0.f), z1 = fmaxf(a1, 0.f);
    float part = z0 * w2[lane] + z1 * w2[64 + lane];
#pragma unroll
    for (int off = 32; off > 0; off >>= 1) part += __shfl_xor(part, off);
    if (lane == 0) out[g] = part + b2[0];
}

// ---------------- launcher ----------------

extern "C" void kernel_launch(void* const* d_in, const int* in_sizes, int n_in,
                              void* d_out, int out_size, void* d_ws, size_t ws_size,
                              hipStream_t stream) {
    const float* x  = (const float*)d_in[0];
    const int*   ei = (const int*)d_in[1];
    const int*   et = (const int*)d_in[2];
    const int*   ui = (const int*)d_in[3];
    const int*   ii = (const int*)d_in[4];
    const float* w1 = (const float*)d_in[21];
    const float* b1 = (const float*)d_in[22];
    const float* w2 = (const float*)d_in[23];
    const float* b2 = (const float*)d_in[24];

    // workspace layout (bytes, all 128-aligned)
    char* ws = (char*)d_ws;
    if (ws_size < 95620608UL) return;           // refuse rather than corrupt
    int*   cnt  = (int*)(ws + 0);               // [500000]
    int*   gcnt = (int*)(ws + 2000000);         // [1]
    int*   offs = (int*)(ws + 2000128);         // [500000]
    int*   cur  = (int*)(ws + 4000128);         // [500000]
    int*   srcs = (int*)(ws + 6000128);         // [3200000]
    float* x32  = (float*)(ws + 18800128);      // [100000*32]  (ping buf A)
    float* hb   = (float*)(ws + 31600128);      // [100000*32]  (ping buf B)
    float* hall = (float*)(ws + 44400128);      // [100000*128]
    float* Wp   = (float*)(ws + 95600128);      // [160*32]

    hipMemsetAsync(cnt, 0, 2000004, stream);    // cnt + gcnt

    k_hist<<<12500, 256, 0, stream>>>(ei, et, cnt);
    k_alloc<<<245, 256, 0, stream>>>(cnt, offs, cur, gcnt);
    k_scatter<<<12500, 256, 0, stream>>>(ei, et, cur, srcs);
    k_pad<<<12500, 256, 0, stream>>>(x, x32);

    float* bufs[2] = {x32, hb};
    for (int l = 0; l < 4; l++) {
        const float* basis = (const float*)d_in[5 + 4 * l];
        const float* comp  = (const float*)d_in[6 + 4 * l];
        const float* root  = (const float*)d_in[7 + 4 * l];
        const float* bias  = (const float*)d_in[8 + 4 * l];
        int in_c = (l == 0) ? 4 : HID;
        k_wprep<<<20, 256, 0, stream>>>(basis, root, in_c, Wp);
        k_layer<<<6250, 256, 0, stream>>>(bufs[l & 1], offs, cnt, srcs, comp, Wp,
                                          bias, bufs[(l + 1) & 1], hall, l * 32);
    }
    k_mlp<<<1024, 256, 0, stream>>>(hall, ui, ii, w1, b1, w2, b2, (float*)d_out);
}

// Round 2
// 895.573 us; speedup vs baseline: 3.5890x; 3.5890x over previous
//
#include <hip/hip_runtime.h>
#include <hip/hip_bf16.h>

#define N_NODES 100000
#define N_EDGES 3200000
#define N_GRAPHS 4096
#define N_REL 5
#define N_BASES 4
#define HID 32
#define SEG (N_NODES*N_REL)

// ---------------- CSR construction ----------------

static __global__ __launch_bounds__(256) void k_hist(const int* __restrict__ ei,
                                                     const int* __restrict__ et,
                                                     int* __restrict__ cnt) {
    int e = blockIdx.x * 256 + threadIdx.x;
    if (e < N_EDGES) {
        int dst = ei[N_EDGES + e];
        int r = et[e];
        atomicAdd(&cnt[dst * N_REL + r], 1);
    }
}

// Block spans 2560 segments (divisible by 5!) so the 5 segments of any node
// get contiguous ascending offsets -> each node is one contiguous edge run.
static __global__ __launch_bounds__(256) void k_alloc(const int* __restrict__ cnt,
                                                      int* __restrict__ offs,
                                                      int* __restrict__ cur,
                                                      int* __restrict__ gcnt) {
    __shared__ int sdata[256];
    __shared__ int sbase;
    int t = threadIdx.x;
    int base = blockIdx.x * 2560 + t * 10;
    int v[10]; int s = 0;
#pragma unroll
    for (int j = 0; j < 10; j++) {
        int idx = base + j;
        int c = (idx < SEG) ? cnt[idx] : 0;
        v[j] = s; s += c;
    }
    sdata[t] = s;
    __syncthreads();
    for (int off = 1; off < 256; off <<= 1) {
        int x = (t >= off) ? sdata[t - off] : 0;
        __syncthreads();
        sdata[t] += x;
        __syncthreads();
    }
    int incl = sdata[t];
    int excl = incl - s;
    if (t == 255) sbase = atomicAdd(gcnt, incl);
    __syncthreads();
    int b0 = sbase + excl;
#pragma unroll
    for (int j = 0; j < 10; j++) {
        int idx = base + j;
        if (idx < SEG) { int o = b0 + v[j]; offs[idx] = o; cur[idx] = o; }
    }
}

static __global__ __launch_bounds__(256) void k_scatter(const int* __restrict__ ei,
                                                        const int* __restrict__ et,
                                                        int* __restrict__ cur,
                                                        int* __restrict__ srcs) {
    int e = blockIdx.x * 256 + threadIdx.x;
    if (e < N_EDGES) {
        int src = ei[e];
        int dst = ei[N_EDGES + e];
        int r = et[e];
        int p = atomicAdd(&cur[dst * N_REL + r], 1);
        srcs[p] = src;
    }
}

// ---------------- layer-0 input padding (4 -> 32 dims, zero fill) ----------------

static __global__ __launch_bounds__(256) void k_pad(const float* __restrict__ x,
                                                    float* __restrict__ x32) {
    int tid = blockIdx.x * 256 + threadIdx.x;
    int n = tid >> 5, i = tid & 31;
    x32[tid] = (i < 4) ? x[(n << 2) + i] : 0.f;
}

// ---------------- per-layer weight prep ----------------
// Wc[k][o], k in [0,160): k<128 -> basis_b rows (b=k>>5, i=k&31, zero-padded),
// k>=128 -> root rows. Packed for float4 phase-2 reads:
// Wp[kc*128 + o*4 + j] = Wc[kc*4+j][o], kc in [0,40).
static __global__ __launch_bounds__(256) void k_wprep(const float* __restrict__ basis,
                                                      const float* __restrict__ root,
                                                      int in_c, float* __restrict__ Wp) {
    int idx = blockIdx.x * 256 + threadIdx.x;   // < 5120
    int kc = idx >> 7, rem = idx & 127;
    int o = rem >> 2, j = rem & 3;
    int k = kc * 4 + j;
    float v;
    if (k < 128) {
        int b = k >> 5, ii = k & 31;
        v = (ii < in_c) ? basis[(b * in_c + ii) * HID + o] : 0.f;
    } else {
        int ii = k - 128;
        v = (ii < in_c) ? root[ii * HID + o] : 0.f;
    }
    Wp[kc * 128 + o * 4 + j] = v;
}

// ---------------- fused RGCN layer ----------------
// Block = 256 = 8 half-waves; half-wave owns a node (lane = dim), 2 nodes
// sequentially -> 16 nodes/block. Node's edges are ONE contiguous run in srcs;
// relation decoded from position vs cumulative boundaries. srcs prefetched 32
// at a time in one coalesced load, broadcast per-edge via shfl -> the 8-deep
// unrolled hin gathers are all independent (high MLP). Per-edge weight
// comp[r][b]/cnt_r is one broadcast ds_read_b128 from a per-node LDS float4.
template <int STRIDE>
static __global__ __launch_bounds__(256, 4) void k_layer(
    const float* __restrict__ hin, const int* __restrict__ offs,
    const int* __restrict__ cnt, const int* __restrict__ srcs,
    const float* __restrict__ comp, const float* __restrict__ Wp,
    const float* __restrict__ bias, float* __restrict__ hall, int hall_off) {
    __shared__ __align__(16) float sAgg[16][160];   // 10 KB
    __shared__ __align__(16) float4 sWc[8][5];      // per-half-wave weight tbl
    int t = threadIdx.x;
    int wave = t >> 6, half = (t >> 5) & 1, i = t & 31;
    int hw = t >> 5;                 // 0..7
    int lbase = half << 5;

    for (int nn = 0; nn < 2; nn++) {
        int nl = hw * 2 + nn;
        int n = blockIdx.x * 16 + nl;            // N_NODES = 6250*16 exactly
        int s5 = n * N_REL;
        int B = offs[s5];
        int c0 = cnt[s5], c1 = cnt[s5+1], c2 = cnt[s5+2], c3 = cnt[s5+3], c4 = cnt[s5+4];
        int b1 = c0, b2 = b1 + c1, b3 = b2 + c2, b4 = b3 + c3, deg = b4 + c4;
        if (i < 20) {
            int r = i >> 2;
            int cc = (r == 0) ? c0 : (r == 1) ? c1 : (r == 2) ? c2 : (r == 3) ? c3 : c4;
            float w = comp[i] * (cc > 0 ? 1.f / (float)cc : 0.f);
            ((float*)&sWc[hw][0])[i] = w;
        }
        float a0 = 0.f, a1 = 0.f, a2 = 0.f, a3 = 0.f;
        for (int cb = 0; cb < deg; cb += 32) {
            int m = deg - cb; if (m > 32) m = 32;
            int p_i = cb + ((i < m) ? i : (m - 1));
            int sv = srcs[B + p_i];                                  // coalesced 128B
            int rv = (p_i >= b1) + (p_i >= b2) + (p_i >= b3) + (p_i >= b4);
            for (int j = 0; j < m; j += 8) {
                int sj[8], rj[8]; float h[8];
#pragma unroll
                for (int q = 0; q < 8; q++) {
                    int jl = j + q; if (jl >= m) jl = m - 1;         // clamp (safe)
                    sj[q] = __shfl(sv, lbase + jl);
                    rj[q] = __shfl(rv, lbase + jl);
                }
#pragma unroll
                for (int q = 0; q < 8; q++) h[q] = hin[sj[q] * STRIDE + i];
#pragma unroll
                for (int q = 0; q < 8; q++) {
                    if (j + q < m) {
                        float4 w4 = sWc[hw][rj[q]];                  // bcast b128
                        a0 += w4.x * h[q]; a1 += w4.y * h[q];
                        a2 += w4.z * h[q]; a3 += w4.w * h[q];
                    }
                }
            }
        }
        sAgg[nl][i]       = a0;
        sAgg[nl][32 + i]  = a1;
        sAgg[nl][64 + i]  = a2;
        sAgg[nl][96 + i]  = a3;
        sAgg[nl][128 + i] = hin[n * STRIDE + i];   // self feature
    }
    __syncthreads();

    // phase 2: K=160 matvec, W float4 from global (L1-resident 20 KB)
    int mynode = wave * 4 + half * 2;
    const float4* wv = (const float4*)Wp;
    const float4* aA = (const float4*)&sAgg[mynode][0];
    const float4* aB = (const float4*)&sAgg[mynode + 1][0];
    float acc0 = 0.f, acc1 = 0.f;
#pragma unroll 8
    for (int kc = 0; kc < 40; kc++) {
        float4 w4 = wv[kc * 32 + i];
        float4 a4 = aA[kc];
        float4 b4 = aB[kc];
        acc0 += a4.x * w4.x + a4.y * w4.y + a4.z * w4.z + a4.w * w4.w;
        acc1 += b4.x * w4.x + b4.y * w4.y + b4.z * w4.z + b4.w * w4.w;
    }
    float bi = bias[i];
    float v0 = tanhf(acc0 + bi);
    float v1 = tanhf(acc1 + bi);
    int n0 = blockIdx.x * 16 + mynode;
    hall[n0 * 128 + hall_off + i] = v0;
    hall[(n0 + 1) * 128 + hall_off + i] = v1;
}

// ---------------- final MLP ----------------
static __global__ __launch_bounds__(256) void k_mlp(
    const float* __restrict__ hall, const int* __restrict__ uidx,
    const int* __restrict__ iidx, const float* __restrict__ w1,
    const float* __restrict__ b1, const float* __restrict__ w2,
    const float* __restrict__ b2, float* __restrict__ out) {
    __shared__ float sg[4][256];
    int t = threadIdx.x, wave = t >> 6, lane = t & 63;
    int g = blockIdx.x * 4 + wave;
    int u = uidx[g], it = iidx[g];
    sg[wave][lane]       = hall[u * 128 + lane];
    sg[wave][64 + lane]  = hall[u * 128 + 64 + lane];
    sg[wave][128 + lane] = hall[it * 128 + lane];
    sg[wave][192 + lane] = hall[it * 128 + 64 + lane];
    __syncthreads();
    float a0 = b1[lane], a1 = b1[64 + lane];
#pragma unroll 4
    for (int k = 0; k < 256; k++) {
        float gk = sg[wave][k];
        a0 += gk * w1[k * 128 + lane];
        a1 += gk * w1[k * 128 + 64 + lane];
    }
    float z0 = fmaxf(a0, 0.f), z1 = fmaxf(a1, 0.f);
    float part = z0 * w2[lane] + z1 * w2[64 + lane];
#pragma unroll
    for (int off = 32; off > 0; off >>= 1) part += __shfl_xor(part, off);
    if (lane == 0) out[g] = part + b2[0];
}

// ---------------- launcher ----------------

extern "C" void kernel_launch(void* const* d_in, const int* in_sizes, int n_in,
                              void* d_out, int out_size, void* d_ws, size_t ws_size,
                              hipStream_t stream) {
    const float* x  = (const float*)d_in[0];
    const int*   ei = (const int*)d_in[1];
    const int*   et = (const int*)d_in[2];
    const int*   ui = (const int*)d_in[3];
    const int*   ii = (const int*)d_in[4];
    const float* w1 = (const float*)d_in[21];
    const float* b1 = (const float*)d_in[22];
    const float* w2 = (const float*)d_in[23];
    const float* b2 = (const float*)d_in[24];

    // workspace layout (bytes)
    char* ws = (char*)d_ws;
    if (ws_size < 82820608UL) return;
    int*   cnt  = (int*)(ws + 0);               // [500000]
    int*   gcnt = (int*)(ws + 2000000);         // [1]
    int*   offs = (int*)(ws + 2000128);         // [500000]
    int*   cur  = (int*)(ws + 4000128);         // [500000]
    int*   srcs = (int*)(ws + 6000128);         // [3200000]
    float* x32  = (float*)(ws + 18800128);      // [100000*32]
    float* hall = (float*)(ws + 31600128);      // [100000*128]
    float* Wp   = (float*)(ws + 82800128);      // [160*32]

    hipMemsetAsync(cnt, 0, 2000004, stream);    // cnt + gcnt

    k_hist<<<12500, 256, 0, stream>>>(ei, et, cnt);
    k_alloc<<<196, 256, 0, stream>>>(cnt, offs, cur, gcnt);
    k_scatter<<<12500, 256, 0, stream>>>(ei, et, cur, srcs);
    k_pad<<<12500, 256, 0, stream>>>(x, x32);

    for (int l = 0; l < 4; l++) {
        const float* basis = (const float*)d_in[5 + 4 * l];
        const float* comp  = (const float*)d_in[6 + 4 * l];
        const float* root  = (const float*)d_in[7 + 4 * l];
        const float* bias  = (const float*)d_in[8 + 4 * l];
        int in_c = (l == 0) ? 4 : HID;
        k_wprep<<<20, 256, 0, stream>>>(basis, root, in_c, Wp);
        if (l == 0) {
            k_layer<32><<<6250, 256, 0, stream>>>(x32, offs, cnt, srcs, comp, Wp,
                                                  bias, hall, 0);
        } else {
            k_layer<128><<<6250, 256, 0, stream>>>(hall + (l - 1) * 32, offs, cnt,
                                                   srcs, comp, Wp, bias, hall, l * 32);
        }
    }
    k_mlp<<<1024, 256, 0, stream>>>(hall, ui, ii, w1, b1, w2, b2, (float*)d_out);
}

// Round 3
// 597.523 us; speedup vs baseline: 5.3792x; 1.4988x over previous
//
#include <hip/hip_runtime.h>
#include <hip/hip_bf16.h>

#define N_NODES 100000
#define N_EDGES 3200000
#define N_GRAPHS 4096
#define N_REL 5
#define N_BASES 4
#define HID 32
#define SEG (N_NODES*N_REL)

#define NBUCK 196        // ceil(100000/512) buckets of 512 dst nodes
#define BCAP  20480      // per-bucket capacity (mean 16327, +32 sigma)
#define NKEY  2560       // 512 nodes * 5 rels per bucket

// ---------------- CSR pass 1: partition edges into dst-range buckets ----------------
// Block tiles 2048 edges. LDS histogram over 196 buckets -> one global atomic
// per (block,bucket) reserves a contiguous run -> packed (lkey,src) records
// land in per-bucket regions with near-full-line write efficiency.
static __global__ __launch_bounds__(256) void k_part(const int* __restrict__ ei,
                                                     const int* __restrict__ et,
                                                     int* __restrict__ gcur,
                                                     unsigned long long* __restrict__ part) {
    __shared__ int hcnt[NBUCK];
    __shared__ int lbase[NBUCK];
    int t = threadIdx.x;
    if (t < NBUCK) hcnt[t] = 0;
    __syncthreads();
    int e0 = blockIdx.x * 2048;
    int src[8], bkt[8], lkey[8];
#pragma unroll
    for (int j = 0; j < 8; j++) {
        int e = e0 + j * 256 + t;
        if (e < N_EDGES) {
            int s = ei[e];
            int d = ei[N_EDGES + e];
            int r = et[e];
            src[j] = s; bkt[j] = d >> 9; lkey[j] = ((d & 511) * 5) + r;
            atomicAdd(&hcnt[bkt[j]], 1);
        } else bkt[j] = -1;
    }
    __syncthreads();
    if (t < NBUCK) lbase[t] = atomicAdd(&gcur[t], hcnt[t]);
    __syncthreads();
    if (t < NBUCK) hcnt[t] = 0;   // reuse as intra-block cursor
    __syncthreads();
#pragma unroll
    for (int j = 0; j < 8; j++) {
        if (bkt[j] >= 0) {
            int rank = atomicAdd(&hcnt[bkt[j]], 1);
            int p = lbase[bkt[j]] + rank;
            if (p < BCAP)
                part[(size_t)bkt[j] * BCAP + p] =
                    ((unsigned long long)(unsigned)lkey[j] << 32) | (unsigned)src[j];
        }
    }
}

// ---------------- CSR pass 2: per-bucket counting sort fully in LDS ----------------
// One block per bucket. Histogram 2560 keys, scan, LDS scatter, coalesced
// writeback of srcs + offs/cnt. No random HBM writes anywhere.
static __global__ __launch_bounds__(512) void k_bsort(const unsigned long long* __restrict__ part,
                                                      const int* __restrict__ gcur,
                                                      int* __restrict__ offs,
                                                      int* __restrict__ cnt,
                                                      int* __restrict__ srcs) {
    __shared__ int lhist[NKEY];      // 10 KB
    __shared__ int lscan[NKEY];      // 10 KB
    __shared__ int lsrc[BCAP];       // 80 KB
    __shared__ int sscan[512];       // 2 KB
    __shared__ int warpsum[8];
    __shared__ int sstart;
    int b = blockIdx.x;
    int t = threadIdx.x;

    // bucket global start = prefix over gcur[0..b)
    int psum = (t < b) ? gcur[t] : 0;
#pragma unroll
    for (int off = 32; off > 0; off >>= 1) psum += __shfl_down(psum, off);
    if ((t & 63) == 0) warpsum[t >> 6] = psum;
    __syncthreads();
    if (t == 0) { int s = 0; for (int w = 0; w < 8; w++) s += warpsum[w]; sstart = s; }
    int n = gcur[b]; if (n > BCAP) n = BCAP;
    const unsigned long long* reg = part + (size_t)b * BCAP;

#pragma unroll
    for (int k = t; k < NKEY; k += 512) lhist[k] = 0;
    __syncthreads();
    for (int i = t; i < n; i += 512) {
        unsigned long long u = reg[i];
        atomicAdd(&lhist[(int)(u >> 32)], 1);
    }
    __syncthreads();

    // exclusive scan over 2560 = 512 threads x 5 keys
    int loc[5]; int s5 = 0;
#pragma unroll
    for (int j = 0; j < 5; j++) { loc[j] = s5; s5 += lhist[t * 5 + j]; }
    sscan[t] = s5;
    __syncthreads();
    for (int off = 1; off < 512; off <<= 1) {
        int x = (t >= off) ? sscan[t - off] : 0;
        __syncthreads();
        sscan[t] += x;
        __syncthreads();
    }
    int excl = sscan[t] - s5;
#pragma unroll
    for (int j = 0; j < 5; j++) lscan[t * 5 + j] = excl + loc[j];
    __syncthreads();

    // write cnt / offs (coalesced); segid = b*2560 + k
    int base = sstart;
#pragma unroll
    for (int j = 0; j < 5; j++) {
        int k = t * 5 + j;
        int segid = b * NKEY + k;
        if (segid < SEG) {
            cnt[segid]  = lhist[k];
            offs[segid] = base + lscan[k];
        }
    }
    __syncthreads();
    // reset hist as scatter cursor
#pragma unroll
    for (int k = t; k < NKEY; k += 512) lhist[k] = 0;
    __syncthreads();
    for (int i = t; i < n; i += 512) {
        unsigned long long u = reg[i];
        int k = (int)(u >> 32);
        int pos = lscan[k] + atomicAdd(&lhist[k], 1);
        lsrc[pos] = (int)(u & 0xffffffffULL);
    }
    __syncthreads();
    for (int i = t; i < n; i += 512) srcs[base + i] = lsrc[i];
}

// ---------------- layer-0 input padding (4 -> 32 dims, zero fill) ----------------

static __global__ __launch_bounds__(256) void k_pad(const float* __restrict__ x,
                                                    float* __restrict__ x32) {
    int tid = blockIdx.x * 256 + threadIdx.x;
    int n = tid >> 5, i = tid & 31;
    x32[tid] = (i < 4) ? x[(n << 2) + i] : 0.f;
}

// ---------------- per-layer weight prep ----------------
static __global__ __launch_bounds__(256) void k_wprep(const float* __restrict__ basis,
                                                      const float* __restrict__ root,
                                                      int in_c, float* __restrict__ Wp) {
    int idx = blockIdx.x * 256 + threadIdx.x;   // < 5120
    int kc = idx >> 7, rem = idx & 127;
    int o = rem >> 2, j = rem & 3;
    int k = kc * 4 + j;
    float v;
    if (k < 128) {
        int b = k >> 5, ii = k & 31;
        v = (ii < in_c) ? basis[(b * in_c + ii) * HID + o] : 0.f;
    } else {
        int ii = k - 128;
        v = (ii < in_c) ? root[ii * HID + o] : 0.f;
    }
    Wp[kc * 128 + o * 4 + j] = v;
}

// ---------------- fused RGCN layer ----------------
template <int STRIDE>
static __global__ __launch_bounds__(256, 4) void k_layer(
    const float* __restrict__ hin, const int* __restrict__ offs,
    const int* __restrict__ cnt, const int* __restrict__ srcs,
    const float* __restrict__ comp, const float* __restrict__ Wp,
    const float* __restrict__ bias, float* __restrict__ hall, int hall_off) {
    __shared__ __align__(16) float sAgg[16][160];   // 10 KB
    __shared__ __align__(16) float4 sWc[8][5];      // per-half-wave weight tbl
    int t = threadIdx.x;
    int wave = t >> 6, half = (t >> 5) & 1, i = t & 31;
    int hw = t >> 5;                 // 0..7
    int lbase = half << 5;

    for (int nn = 0; nn < 2; nn++) {
        int nl = hw * 2 + nn;
        int n = blockIdx.x * 16 + nl;            // N_NODES = 6250*16 exactly
        int s5 = n * N_REL;
        int B = offs[s5];
        int c0 = cnt[s5], c1 = cnt[s5+1], c2 = cnt[s5+2], c3 = cnt[s5+3], c4 = cnt[s5+4];
        int b1 = c0, b2 = b1 + c1, b3 = b2 + c2, b4 = b3 + c3, deg = b4 + c4;
        if (i < 20) {
            int r = i >> 2;
            int cc = (r == 0) ? c0 : (r == 1) ? c1 : (r == 2) ? c2 : (r == 3) ? c3 : c4;
            float w = comp[i] * (cc > 0 ? 1.f / (float)cc : 0.f);
            ((float*)&sWc[hw][0])[i] = w;
        }
        float a0 = 0.f, a1 = 0.f, a2 = 0.f, a3 = 0.f;
        for (int cb = 0; cb < deg; cb += 32) {
            int m = deg - cb; if (m > 32) m = 32;
            int p_i = cb + ((i < m) ? i : (m - 1));
            int sv = srcs[B + p_i];                                  // coalesced 128B
            int rv = (p_i >= b1) + (p_i >= b2) + (p_i >= b3) + (p_i >= b4);
            for (int j = 0; j < m; j += 8) {
                int sj[8], rj[8]; float h[8];
#pragma unroll
                for (int q = 0; q < 8; q++) {
                    int jl = j + q; if (jl >= m) jl = m - 1;         // clamp (safe)
                    sj[q] = __shfl(sv, lbase + jl);
                    rj[q] = __shfl(rv, lbase + jl);
                }
#pragma unroll
                for (int q = 0; q < 8; q++) h[q] = hin[sj[q] * STRIDE + i];
#pragma unroll
                for (int q = 0; q < 8; q++) {
                    if (j + q < m) {
                        float4 w4 = sWc[hw][rj[q]];                  // bcast b128
                        a0 += w4.x * h[q]; a1 += w4.y * h[q];
                        a2 += w4.z * h[q]; a3 += w4.w * h[q];
                    }
                }
            }
        }
        sAgg[nl][i]       = a0;
        sAgg[nl][32 + i]  = a1;
        sAgg[nl][64 + i]  = a2;
        sAgg[nl][96 + i]  = a3;
        sAgg[nl][128 + i] = hin[n * STRIDE + i];   // self feature
    }
    __syncthreads();

    // phase 2: K=160 matvec, W float4 from global (L1-resident 20 KB)
    int mynode = wave * 4 + half * 2;
    const float4* wv = (const float4*)Wp;
    const float4* aA = (const float4*)&sAgg[mynode][0];
    const float4* aB = (const float4*)&sAgg[mynode + 1][0];
    float acc0 = 0.f, acc1 = 0.f;
#pragma unroll 8
    for (int kc = 0; kc < 40; kc++) {
        float4 w4 = wv[kc * 32 + i];
        float4 a4 = aA[kc];
        float4 b4 = aB[kc];
        acc0 += a4.x * w4.x + a4.y * w4.y + a4.z * w4.z + a4.w * w4.w;
        acc1 += b4.x * w4.x + b4.y * w4.y + b4.z * w4.z + b4.w * w4.w;
    }
    float bi = bias[i];
    float v0 = tanhf(acc0 + bi);
    float v1 = tanhf(acc1 + bi);
    int n0 = blockIdx.x * 16 + mynode;
    hall[n0 * 128 + hall_off + i] = v0;
    hall[(n0 + 1) * 128 + hall_off + i] = v1;
}

// ---------------- final MLP ----------------
static __global__ __launch_bounds__(256) void k_mlp(
    const float* __restrict__ hall, const int* __restrict__ uidx,
    const int* __restrict__ iidx, const float* __restrict__ w1,
    const float* __restrict__ b1, const float* __restrict__ w2,
    const float* __restrict__ b2, float* __restrict__ out) {
    __shared__ float sg[4][256];
    int t = threadIdx.x, wave = t >> 6, lane = t & 63;
    int g = blockIdx.x * 4 + wave;
    int u = uidx[g], it = iidx[g];
    sg[wave][lane]       = hall[u * 128 + lane];
    sg[wave][64 + lane]  = hall[u * 128 + 64 + lane];
    sg[wave][128 + lane] = hall[it * 128 + lane];
    sg[wave][192 + lane] = hall[it * 128 + 64 + lane];
    __syncthreads();
    float a0 = b1[lane], a1 = b1[64 + lane];
#pragma unroll 4
    for (int k = 0; k < 256; k++) {
        float gk = sg[wave][k];
        a0 += gk * w1[k * 128 + lane];
        a1 += gk * w1[k * 128 + 64 + lane];
    }
    float z0 = fmaxf(a0, 0.f), z1 = fmaxf(a1, 0.f);
    float part = z0 * w2[lane] + z1 * w2[64 + lane];
#pragma unroll
    for (int off = 32; off > 0; off >>= 1) part += __shfl_xor(part, off);
    if (lane == 0) out[g] = part + b2[0];
}

// ---------------- launcher ----------------

extern "C" void kernel_launch(void* const* d_in, const int* in_sizes, int n_in,
                              void* d_out, int out_size, void* d_ws, size_t ws_size,
                              hipStream_t stream) {
    const float* x  = (const float*)d_in[0];
    const int*   ei = (const int*)d_in[1];
    const int*   et = (const int*)d_in[2];
    const int*   ui = (const int*)d_in[3];
    const int*   ii = (const int*)d_in[4];
    const float* w1 = (const float*)d_in[21];
    const float* b1 = (const float*)d_in[22];
    const float* w2 = (const float*)d_in[23];
    const float* b2 = (const float*)d_in[24];

    // workspace layout (bytes, 128-aligned). part aliases hall (dead until layers).
    char* ws = (char*)d_ws;
    if (ws_size < 80821504UL) return;
    int*   gcur = (int*)(ws + 0);               // [196]
    int*   offs = (int*)(ws + 1024);            // [500000]
    int*   cnt  = (int*)(ws + 2001024);         // [500000]
    int*   srcs = (int*)(ws + 4001024);         // [3200000]
    float* x32  = (float*)(ws + 16801024);      // [100000*32]
    float* Wp   = (float*)(ws + 29601024);      // [160*32]
    float* hall = (float*)(ws + 29621504);      // [100000*128] = 51.2 MB
    unsigned long long* part = (unsigned long long*)(ws + 29621504);  // alias, 32.1 MB

    hipMemsetAsync(gcur, 0, NBUCK * 4, stream);

    k_part<<<1563, 256, 0, stream>>>(ei, et, gcur, part);
    k_bsort<<<NBUCK, 512, 0, stream>>>(part, gcur, offs, cnt, srcs);
    k_pad<<<12500, 256, 0, stream>>>(x, x32);

    for (int l = 0; l < 4; l++) {
        const float* basis = (const float*)d_in[5 + 4 * l];
        const float* comp  = (const float*)d_in[6 + 4 * l];
        const float* root  = (const float*)d_in[7 + 4 * l];
        const float* bias  = (const float*)d_in[8 + 4 * l];
        int in_c = (l == 0) ? 4 : HID;
        k_wprep<<<20, 256, 0, stream>>>(basis, root, in_c, Wp);
        if (l == 0) {
            k_layer<32><<<6250, 256, 0, stream>>>(x32, offs, cnt, srcs, comp, Wp,
                                                  bias, hall, 0);
        } else {
            k_layer<128><<<6250, 256, 0, stream>>>(hall + (l - 1) * 32, offs, cnt,
                                                   srcs, comp, Wp, bias, hall, l * 32);
        }
    }
    k_mlp<<<1024, 256, 0, stream>>>(hall, ui, ii, w1, b1, w2, b2, (float*)d_out);
}